// Round 6
// baseline (508.536 us; speedup 1.0000x reference)
//
#include <hip/hip_runtime.h>

#define D_   256
#define HW_  1024
#define N_   65536
#define K_   1024
#define ND_  16777216
// one-sided fp16 phase1 score error bound: S1*A + B (conservative ~2x)
#define MARGIN_A 2.2e-6f
#define MARGIN_B 6.0e-5f

typedef __attribute__((ext_vector_type(8))) short bf16x8;
typedef __attribute__((ext_vector_type(8))) _Float16 f16x8;
typedef __attribute__((ext_vector_type(4))) float f32x4;

union f16cv { _Float16 h; unsigned short u; };

__device__ inline unsigned short f16_bits(float v) {
    f16cv c; c.h = (_Float16)v; return c.u;
}

__device__ inline void ins4(float v, int i,
                            float& r0, int& q0, float& r1, int& q1,
                            float& r2, int& q2, float& r3, int& q3) {
    if (v < r0 || (v == r0 && i < q0)) { r3=r2;q3=q2; r2=r1;q2=q1; r1=r0;q1=q0; r0=v;q0=i; }
    else if (v < r1 || (v == r1 && i < q1)) { r3=r2;q3=q2; r2=r1;q2=q1; r1=v;q1=i; }
    else if (v < r2 || (v == r2 && i < q2)) { r3=r2;q3=q2; r2=v;q2=i; }
    else if (v < r3 || (v == r3 && i < q3)) { r3=v;q3=i; }
}

#define GLL16(g, l) __builtin_amdgcn_global_load_lds( \
    (const __attribute__((address_space(1))) unsigned int*)(const void*)(g), \
    (__attribute__((address_space(3))) unsigned int*)(void*)(l), 16, 0, 0)

// ---- k_init: E -> f16 (x1024) + Et (f32 transpose) + e2 (f32/f64) + zeros ----
__global__ __launch_bounds__(256) void k_init(const float* __restrict__ E,
                                              unsigned short* __restrict__ Eh,
                                              float* __restrict__ Et,
                                              float* __restrict__ e2f,
                                              double* __restrict__ e2d,
                                              int* __restrict__ counts,
                                              int* __restrict__ nflag1,
                                              int* __restrict__ nflag2,
                                              double* __restrict__ loss_acc) {
    __shared__ double sh[256];
    int k = blockIdx.x, t = threadIdx.x;            // grid = 1024
    float v = E[(size_t)k * D_ + t];
    Eh[(size_t)k * D_ + t] = f16_bits(v * 1024.f);  // exact pow2 scale
    Et[(size_t)t * K_ + k] = v;
    sh[t] = (double)v * v;
    __syncthreads();
    for (int off = 128; off; off >>= 1) {
        if (t < off) sh[t] += sh[t + off];
        __syncthreads();
    }
    if (t == 0) {
        e2f[k] = (float)sh[0];
        e2d[k] = sh[0];
        counts[k] = 0;
        if (k == 0) { *loss_acc = 0.0; *nflag1 = 0; *nflag2 = 0; }
    }
}

// ---- k_zsplit: Z [b][d][hw] fp32 -> Zh [n][d] f16 + S1[n] = sum|z_d| ----
__global__ __launch_bounds__(256) void k_zsplit(const float* __restrict__ Z,
                                                unsigned short* __restrict__ Zh,
                                                float* __restrict__ S1) {
    __shared__ unsigned short lh[32][264];
    __shared__ float sabs[32][8];
    int t = threadIdx.x;
    int bid = blockIdx.x;                 // 2048 = 64 b * 32 chunks
    int b = bid >> 5, hw0 = (bid & 31) * 32;
    int hw = t & 31, dq = t >> 5;         // dq 0..7
    const float* zb = Z + (size_t)b * (D_ * HW_) + hw0;
    float asum = 0.f;
    #pragma unroll 8
    for (int j = 0; j < 32; ++j) {
        int d = j * 8 + dq;
        float v = zb[(size_t)d * HW_ + hw];
        lh[hw][d] = f16_bits(v);
        asum += fabsf(v);
    }
    sabs[hw][dq] = asum;
    __syncthreads();
    int row = t >> 3, cb = t & 7;
    size_t nbase = ((size_t)b * HW_ + hw0 + row) * D_;
    #pragma unroll
    for (int jj = 0; jj < 4; ++jj) {
        int ch = cb + jj * 8;
        *(bf16x8*)(Zh + nbase + ch * 8) = *(const bf16x8*)&lh[row][ch * 8];
    }
    if (t < 32) {
        float s = 0.f;
        #pragma unroll
        for (int q = 0; q < 8; ++q) s += sabs[t][q];
        S1[(size_t)b * HW_ + hw0 + t] = s;
    }
}

// ---- k_phase1: 128x128 f16 MFMA GEMM + per-block top-2 partials (XCD-remapped) ----
__global__ __launch_bounds__(256) void k_phase1(const unsigned short* __restrict__ Zh,
                                                const unsigned short* __restrict__ Eh,
                                                const float* __restrict__ e2f,
                                                float* __restrict__ pm1,
                                                float* __restrict__ pm2,
                                                int* __restrict__ pi1) {
    __shared__ __align__(16) unsigned short lds[2 * 8192];  // A [128][64], B [128][64]
    int t = threadIdx.x, w = t >> 6, l = t & 63;
    int bid = blockIdx.x;
    // XCD-aware remap: all 8 nb-siblings of an mb run on the SAME XCD (A-tile L2-hot)
    int xcd = bid & 7, slot = bid >> 3;
    int mb = xcd * 64 + (slot >> 3);
    int nb = slot & 7;
    int wr = w >> 1, wc = w & 1;

    const unsigned short* src =
        (w < 2 ? Zh + (size_t)mb * 128 * D_ : Eh + (size_t)nb * 128 * D_)
        + (size_t)(w & 1) * 64 * D_;
    unsigned short* myl = &lds[__builtin_amdgcn_readfirstlane((w >> 1) * 8192 + (w & 1) * 4096)];

    int Rl = l >> 3;
    int lc = (l & 7) ^ (l >> 3);           // pre-swizzled source chunk (rule #21)

    f32x4 acc[4][4];
    #pragma unroll
    for (int m = 0; m < 4; ++m)
        #pragma unroll
        for (int nn = 0; nn < 4; ++nn) acc[m][nn] = (f32x4){0.f, 0.f, 0.f, 0.f};

    for (int kt = 0; kt < 4; ++kt) {
        #pragma unroll
        for (int i = 0; i < 8; ++i) {
            const unsigned short* g = src + (size_t)(i * 8 + Rl) * D_ + kt * 64 + lc * 8;
            GLL16(g, myl + i * 512);
        }
        __syncthreads();
        int q = l >> 4;
        #pragma unroll
        for (int ks2 = 0; ks2 < 2; ++ks2) {
            int pcb = ((ks2 * 4 + q) ^ (l & 7)) * 16;  // swizzled chunk byte offset
            f16x8 ah[4];
            #pragma unroll
            for (int m = 0; m < 4; ++m)
                ah[m] = *(const f16x8*)((const char*)&lds[0] + (wr * 64 + m * 16 + (l & 15)) * 128 + pcb);
            #pragma unroll
            for (int nn = 0; nn < 4; ++nn) {
                f16x8 bh = *(const f16x8*)((const char*)&lds[8192] + (wc * 64 + nn * 16 + (l & 15)) * 128 + pcb);
                #pragma unroll
                for (int m = 0; m < 4; ++m)
                    acc[m][nn] = __builtin_amdgcn_mfma_f32_16x16x32_f16(ah[m], bh, acc[m][nn], 0, 0, 0);
            }
        }
        __syncthreads();
    }

    // ---- cheap top-2 epilogue (round-4-proven) ----
    float m1v[4][4], m2v[4][4]; int i1v[4][4];   // [m][r]
    #pragma unroll
    for (int m = 0; m < 4; ++m)
        #pragma unroll
        for (int r = 0; r < 4; ++r) { m1v[m][r] = 3.4e38f; m2v[m][r] = 3.4e38f; i1v[m][r] = 0; }

    #pragma unroll
    for (int nn = 0; nn < 4; ++nn) {
        int c = nb * 128 + wc * 64 + nn * 16 + (l & 15);
        float e2 = e2f[c];
        #pragma unroll
        for (int m = 0; m < 4; ++m)
            #pragma unroll
            for (int r = 0; r < 4; ++r) {
                float s = fmaf(-2.f / 1024.f, acc[m][nn][r], e2);   // unscale dot
                if (s < m1v[m][r])      { m2v[m][r] = m1v[m][r]; m1v[m][r] = s; i1v[m][r] = c; }
                else if (s < m2v[m][r]) { m2v[m][r] = s; }
            }
    }
    #pragma unroll
    for (int off = 1; off < 16; off <<= 1) {
        #pragma unroll
        for (int m = 0; m < 4; ++m)
            #pragma unroll
            for (int r = 0; r < 4; ++r) {
                float o1 = __shfl_xor(m1v[m][r], off, 64);
                float o2 = __shfl_xor(m2v[m][r], off, 64);
                int   oi = __shfl_xor(i1v[m][r], off, 64);
                if (o1 < m1v[m][r]) { m2v[m][r] = fminf(m1v[m][r], o2); m1v[m][r] = o1; i1v[m][r] = oi; }
                else                { m2v[m][r] = fminf(m2v[m][r], o1); }
            }
    }
    __syncthreads();                       // reuse lds as exchange
    float* ex1 = (float*)lds;              // [4 waves][64 rows]
    float* ex2 = ex1 + 256;
    int*   exi = (int*)(ex2 + 256);
    if ((l & 15) == 0) {
        int qq = l >> 4;
        #pragma unroll
        for (int m = 0; m < 4; ++m)
            #pragma unroll
            for (int r = 0; r < 4; ++r) {
                int e = (wr * 2 + wc) * 64 + m * 16 + qq * 4 + r;
                ex1[e] = m1v[m][r]; ex2[e] = m2v[m][r]; exi[e] = i1v[m][r];
            }
    }
    __syncthreads();
    if (t < 128) {
        int wr2 = t >> 6, rw = t & 63;
        int e0 = (wr2 * 2 + 0) * 64 + rw, e1 = (wr2 * 2 + 1) * 64 + rw;
        float a1 = ex1[e0], a2 = ex2[e0]; int ai = exi[e0];
        float b1 = ex1[e1], b2 = ex2[e1]; int bi = exi[e1];
        float M1, M2; int I1;
        if (a1 <= b1) { M1 = a1; I1 = ai; M2 = fminf(a2, b1); }
        else          { M1 = b1; I1 = bi; M2 = fminf(b2, a1); }
        size_t p = (size_t)nb * N_ + (size_t)mb * 128 + t;
        pm1[p] = M1; pm2[p] = M2; pi1[p] = I1;
    }
}

// ---- k_merge: fold 8 top-2 partials -> idx, counts, compacted flagged list ----
__global__ __launch_bounds__(256) void k_merge(const float* __restrict__ pm1,
                                               const float* __restrict__ pm2,
                                               const int* __restrict__ pi1,
                                               const float* __restrict__ S1,
                                               int* __restrict__ idx,
                                               int* __restrict__ counts,
                                               unsigned char* __restrict__ flag,
                                               int* __restrict__ list1,
                                               int* __restrict__ nflag1) {
    int n = blockIdx.x * 256 + threadIdx.x;     // grid = 256
    float M1 = 3.4e38f, M2 = 3.4e38f; int I1 = 0;
    #pragma unroll
    for (int nb = 0; nb < 8; ++nb) {
        size_t p = (size_t)nb * N_ + n;
        float a1 = pm1[p], a2 = pm2[p]; int ai = pi1[p];
        if (a1 < M1) { M2 = fminf(M1, a2); M1 = a1; I1 = ai; }
        else         { M2 = fminf(M2, a1); }
    }
    idx[n] = I1;
    atomicAdd(&counts[I1], 1);
    bool fl = (M2 - M1) < fmaf(S1[n], MARGIN_A, MARGIN_B);
    flag[n] = fl ? 1 : 0;
    unsigned long long mask = __ballot(fl);
    int lane = threadIdx.x & 63;
    int cnt = __popcll(mask);
    if (cnt) {
        int base = 0;
        if (lane == 0) base = atomicAdd(nflag1, cnt);
        base = __shfl(base, 0, 64);
        if (fl) {
            int pos = __popcll(mask & ((1ull << lane) - 1ull));
            list1[base + pos] = n;
        }
    }
}

// ---- k_candsel: compact f16 GEMM over flagged rows -> top-4 candidates ----
__global__ __launch_bounds__(256) void k_candsel(const unsigned short* __restrict__ Zh,
                                                 const unsigned short* __restrict__ Eh,
                                                 const float* __restrict__ e2f,
                                                 const float* __restrict__ S1,
                                                 const int* __restrict__ list1,
                                                 const int* __restrict__ nflag1,
                                                 int4* __restrict__ c4,
                                                 unsigned char* __restrict__ flag,
                                                 int* __restrict__ list2,
                                                 int* __restrict__ nflag2) {
    __shared__ __align__(16) unsigned short ldsA[32768];  // 64KB: [kt][128 rows][64 d]
    __shared__ __align__(16) unsigned short ldsB[8192];   // 16KB: [128 codes][64 d] / exv-exi
    __shared__ int snl[128];
    int t = threadIdx.x, w = t >> 6, l = t & 63;
    int wr = w >> 1, wc = w & 1;
    int lc = (l & 7) ^ (l >> 3);           // pre-swizzled source chunk
    int nf = *nflag1;

    for (int chunk = blockIdx.x; chunk * 128 < nf; chunk += gridDim.x) {
        __syncthreads();                   // protect snl/ldsA from previous iteration
        int i0 = chunk * 128;
        int cnt = min(128, nf - i0);
        if (t < 128) snl[t] = list1[i0 + min(t, cnt - 1)];
        __syncthreads();

        // stage A: full K resident; wave w covers rows w*32 .. w*32+31 (gathered rows)
        #pragma unroll
        for (int kt = 0; kt < 4; ++kt)
            #pragma unroll
            for (int i = 0; i < 4; ++i) {
                int rbase = w * 32 + i * 8;
                int n = snl[rbase + (l >> 3)];
                const unsigned short* g = Zh + (size_t)n * D_ + kt * 64 + lc * 8;
                GLL16(g, ldsA + kt * 8192 + rbase * 64);
            }

        float r0 = 3.4e38f, r1 = 3.4e38f, r2 = 3.4e38f, r3 = 3.4e38f;
        int q0 = 0, q1 = 0, q2 = 0, q3 = 0;

        for (int nb = 0; nb < 8; ++nb) {
            f32x4 acc[4][4];
            #pragma unroll
            for (int m = 0; m < 4; ++m)
                #pragma unroll
                for (int nn = 0; nn < 4; ++nn) acc[m][nn] = (f32x4){0.f, 0.f, 0.f, 0.f};

            for (int kt = 0; kt < 4; ++kt) {
                #pragma unroll
                for (int i = 0; i < 4; ++i) {
                    int rbase = w * 32 + i * 8;
                    const unsigned short* g = Eh + (size_t)(nb * 128 + rbase + (l >> 3)) * D_ + kt * 64 + lc * 8;
                    GLL16(g, ldsB + rbase * 64);
                }
                __syncthreads();
                int qh = l >> 4;
                #pragma unroll
                for (int ks2 = 0; ks2 < 2; ++ks2) {
                    int pcb = ((ks2 * 4 + qh) ^ (l & 7)) * 16;
                    f16x8 ah[4];
                    #pragma unroll
                    for (int m = 0; m < 4; ++m)
                        ah[m] = *(const f16x8*)((const char*)ldsA + kt * 16384 + (wr * 64 + m * 16 + (l & 15)) * 128 + pcb);
                    #pragma unroll
                    for (int nn = 0; nn < 4; ++nn) {
                        f16x8 bh = *(const f16x8*)((const char*)ldsB + (wc * 64 + nn * 16 + (l & 15)) * 128 + pcb);
                        #pragma unroll
                        for (int m = 0; m < 4; ++m)
                            acc[m][nn] = __builtin_amdgcn_mfma_f32_16x16x32_f16(ah[m], bh, acc[m][nn], 0, 0, 0);
                    }
                }
                __syncthreads();
            }

            // scores in place
            #pragma unroll
            for (int nn = 0; nn < 4; ++nn) {
                int c = nb * 128 + wc * 64 + nn * 16 + (l & 15);
                float e2 = e2f[c];
                #pragma unroll
                for (int m = 0; m < 4; ++m)
                    #pragma unroll
                    for (int r = 0; r < 4; ++r)
                        acc[m][nn][r] = fmaf(-2.f / 1024.f, acc[m][nn][r], e2);
            }

            // expensive top-4 extraction (amortized: ~51 blocks only)
            float* exv = (float*)ldsB;     // [128 rows][2 halves][4]
            int*   exi = (int*)(exv + 1024);
            int cl = nb * 128 + wc * 64 + (l & 15);
            int qq = l >> 4;
            #pragma unroll
            for (int m = 0; m < 4; ++m)
                #pragma unroll
                for (int r = 0; r < 4; ++r) {
                    #pragma unroll
                    for (int p = 0; p < 4; ++p) {
                        float lv = acc[m][0][r]; int lcw = cl;
                        #pragma unroll
                        for (int nn = 1; nn < 4; ++nn) {
                            float v = acc[m][nn][r]; int cc = cl + nn * 16;
                            if (v < lv || (v == lv && cc < lcw)) { lv = v; lcw = cc; }
                        }
                        #pragma unroll
                        for (int off = 1; off < 16; off <<= 1) {
                            float ov = __shfl_xor(lv, off, 64);
                            int   oc = __shfl_xor(lcw, off, 64);
                            if (ov < lv || (ov == lv && oc < lcw)) { lv = ov; lcw = oc; }
                        }
                        #pragma unroll
                        for (int nn = 0; nn < 4; ++nn)
                            if (cl + nn * 16 == lcw) acc[m][nn][r] = 3.4e38f;
                        if ((l & 15) == 0) {
                            int row = wr * 64 + m * 16 + qq * 4 + r;
                            exv[(row * 2 + wc) * 4 + p] = lv;
                            exi[(row * 2 + wc) * 4 + p] = lcw;
                        }
                    }
                }
            __syncthreads();
            if (t < 128) {
                #pragma unroll
                for (int half = 0; half < 2; ++half)
                    #pragma unroll
                    for (int j = 0; j < 4; ++j)
                        ins4(exv[(t * 2 + half) * 4 + j], exi[(t * 2 + half) * 4 + j],
                             r0, q0, r1, q1, r2, q2, r3, q3);
            }
            __syncthreads();               // exv region reused as B next nb
        }

        // classify: top-4 sufficient (c4) vs full fallback (list2)
        bool full = false;
        int n = -1;
        if (t < cnt) {
            n = snl[t];
            float eps = fmaf(S1[n], MARGIN_A, MARGIN_B);
            if (r3 - r0 < eps) { full = true; flag[n] = 0; }
            else               c4[n] = make_int4(q0, q1, q2, q3);
        }
        unsigned long long mask = __ballot(full);
        int cf = __popcll(mask);
        if (cf) {
            int base = 0;
            if (l == 0) base = atomicAdd(nflag2, cf);
            base = __shfl(base, 0, 64);
            if (full) {
                int pos = __popcll(mask & ((1ull << l) - 1ull));
                list2[base + pos] = n;
            }
        }
    }
}

// ---- k_rescan: exact f64 full-K fallback (expected ~0 items) ----
__global__ __launch_bounds__(256) void k_rescan(const float* __restrict__ Z,
                                                const float* __restrict__ Et,
                                                const double* __restrict__ e2d,
                                                const int* __restrict__ list2,
                                                const int* __restrict__ nflag2,
                                                int* __restrict__ idx,
                                                int* __restrict__ counts) {
    __shared__ float  zs[256];
    __shared__ double rv[256];
    __shared__ int    ri[256];
    int t = threadIdx.x;
    int nf = *nflag2;
    for (int ii = blockIdx.x; ii < nf; ii += 512) {      // grid = 512
        int n = list2[ii];
        int b = n >> 10, hw = n & (HW_ - 1);
        zs[t] = Z[(size_t)b * (D_ * HW_) + (size_t)t * HW_ + hw];
        __syncthreads();
        rv[t] = (double)zs[t] * (double)zs[t];
        __syncthreads();
        for (int off = 128; off; off >>= 1) {
            if (t < off) rv[t] += rv[t + off];
            __syncthreads();
        }
        double z2 = rv[0];
        __syncthreads();

        double s0 = 0.0, s1 = 0.0, s2 = 0.0, s3 = 0.0;
        #pragma unroll 4
        for (int d = 0; d < 256; ++d) {
            double zv = (double)zs[d];
            float4 e4 = *(const float4*)(Et + (size_t)d * K_ + 4 * t);
            s0 = fma(zv, (double)e4.x, s0);
            s1 = fma(zv, (double)e4.y, s1);
            s2 = fma(zv, (double)e4.z, s2);
            s3 = fma(zv, (double)e4.w, s3);
        }
        double best = 1e300; int bi = 0;
        double dvv[4] = { fma(-2.0, s0, z2 + e2d[4 * t + 0]),
                          fma(-2.0, s1, z2 + e2d[4 * t + 1]),
                          fma(-2.0, s2, z2 + e2d[4 * t + 2]),
                          fma(-2.0, s3, z2 + e2d[4 * t + 3]) };
        #pragma unroll
        for (int c = 0; c < 4; ++c)
            if (dvv[c] < best) { best = dvv[c]; bi = 4 * t + c; }
        rv[t] = best; ri[t] = bi;
        __syncthreads();
        for (int off = 128; off; off >>= 1) {
            if (t < off) {
                double ov = rv[t + off]; int oi = ri[t + off];
                if (ov < rv[t] || (ov == rv[t] && oi < ri[t])) { rv[t] = ov; ri[t] = oi; }
            }
            __syncthreads();
        }
        if (t == 0) {
            int I = ri[0], old = idx[n];
            if (I != old) {
                idx[n] = I;
                atomicSub(&counts[old], 1);
                atomicAdd(&counts[I], 1);
            }
        }
        __syncthreads();
    }
}

// ---- k_gather: fused c4 f64 rescore + z_q out (NCHW) + f64 loss ----
__global__ __launch_bounds__(256) void k_gather(const float* __restrict__ Z,
                                                const float* __restrict__ E,
                                                const int* __restrict__ idx,
                                                const unsigned char* __restrict__ flag,
                                                const int4* __restrict__ c4,
                                                float* __restrict__ out_zq,
                                                int* __restrict__ counts,
                                                double* __restrict__ loss_acc) {
    __shared__ float zs[32][257];
    __shared__ float ecache[32][257];
    __shared__ int sidx[32];
    __shared__ unsigned char sflag[32];
    __shared__ double dv[4];
    __shared__ double wls[4];
    int t = threadIdx.x;
    int n0 = blockIdx.x * 32;                 // grid = 2048
    int b = n0 >> 10, hw0 = n0 & (HW_ - 1);
    if (t < 32) { sidx[t] = idx[n0 + t]; sflag[t] = flag[n0 + t]; }

    int hw = t & 31, cq = t >> 5;
    const float* zb = Z + (size_t)b * (D_ * HW_) + hw0 + hw;
    #pragma unroll 4
    for (int jj = 0; jj < 32; ++jj) {
        int c = cq * 32 + jj;
        zs[hw][c] = zb[(size_t)c * HW_];      // coalesced
    }
    __syncthreads();

    // f64 rescore of flagged rows' 4 candidates (uniform branches via LDS flags)
    int wj = t >> 6, l = t & 63;
    for (int hwi = 0; hwi < 32; ++hwi) {
        if (!sflag[hwi]) continue;
        int4 cd = c4[n0 + hwi];
        int cj = (wj == 0) ? cd.x : (wj == 1) ? cd.y : (wj == 2) ? cd.z : cd.w;
        const float* er = E + (size_t)cj * D_;
        double s = 0.0;
        #pragma unroll
        for (int q = 0; q < 4; ++q) {
            int d = l + q * 64;
            double dz = (double)zs[hwi][d] - (double)er[d];
            s = fma(dz, dz, s);
        }
        #pragma unroll
        for (int off = 32; off; off >>= 1) s += __shfl_xor(s, off, 64);
        if (l == 0) dv[wj] = s;
        __syncthreads();
        if (t == 0) {
            double bv = dv[0]; int bi = cd.x;
            if (dv[1] < bv || (dv[1] == bv && cd.y < bi)) { bv = dv[1]; bi = cd.y; }
            if (dv[2] < bv || (dv[2] == bv && cd.z < bi)) { bv = dv[2]; bi = cd.z; }
            if (dv[3] < bv || (dv[3] == bv && cd.w < bi)) { bv = dv[3]; bi = cd.w; }
            int old = sidx[hwi];
            if (bi != old) {
                sidx[hwi] = bi;
                atomicSub(&counts[old], 1);
                atomicAdd(&counts[bi], 1);
            }
        }
        __syncthreads();
    }
    __syncthreads();

    #pragma unroll 8
    for (int j = 0; j < 32; ++j)
        ecache[j][t] = E[(size_t)sidx[j] * D_ + t];
    __syncthreads();

    float* ob = out_zq + (size_t)b * (D_ * HW_) + hw0 + hw;
    double ls = 0.0;
    #pragma unroll 4
    for (int jj = 0; jj < 32; ++jj) {
        int c = cq * 32 + jj;
        float e = ecache[hw][c];
        float z = zs[hw][c];
        ob[(size_t)c * HW_] = e;
        double dz = (double)z - (double)e;
        ls = fma(dz, dz, ls);
    }
    #pragma unroll
    for (int off = 32; off; off >>= 1) ls += __shfl_xor(ls, off, 64);
    int wv = t >> 6;
    if ((t & 63) == 0) wls[wv] = ls;
    __syncthreads();
    if (t == 0) atomicAdd(loss_acc, wls[0] + wls[1] + wls[2] + wls[3]);
}

// ---- k_final ----
__global__ __launch_bounds__(256) void k_final(const int* __restrict__ counts,
                                               const double* __restrict__ loss_acc,
                                               float* __restrict__ out) {
    __shared__ double sh[256];
    int t = threadIdx.x;
    double s = 0.0;
    for (int k = t; k < K_; k += 256) {
        double p = (double)counts[k] / (double)N_;
        s += p * log(p + 1e-10);
    }
    sh[t] = s; __syncthreads();
    for (int off = 128; off; off >>= 1) {
        if (t < off) sh[t] += sh[t + off];
        __syncthreads();
    }
    if (t == 0) {
        out[0]       = (float)((*loss_acc) / (double)ND_ * 1.25);
        out[1 + ND_] = (float)exp(-sh[0]);
    }
}

extern "C" void kernel_launch(void* const* d_in, const int* in_sizes, int n_in,
                              void* d_out, int out_size, void* d_ws, size_t ws_size,
                              hipStream_t stream) {
    (void)in_sizes; (void)n_in; (void)out_size; (void)ws_size;
    const float* Z = (const float*)d_in[0];
    const float* E = (const float*)d_in[1];
    float* out = (float*)d_out;

    char* ws = (char*)d_ws;
    unsigned short* Zh       = (unsigned short*)(ws);              // 32 MB
    unsigned short* Eh       = (unsigned short*)(ws + 33554432);   // 512 KB
    float*          Et       = (float*)(ws + 34078720);            // 1 MB
    float*          e2f      = (float*)(ws + 35127296);            // 4 KB
    double*         e2d      = (double*)(ws + 35131392);           // 8 KB
    float*          S1       = (float*)(ws + 35139584);            // 256 KB
    float*          pm1      = (float*)(ws + 35401728);            // 2 MB
    float*          pm2      = (float*)(ws + 37498880);            // 2 MB
    int*            pi1      = (int*)  (ws + 39596032);            // 2 MB
    int*            idx      = (int*)  (ws + 41693184);            // 256 KB
    unsigned char*  flag     = (unsigned char*)(ws + 41955328);    // 64 KB
    int*            list1    = (int*)  (ws + 42020864);            // 256 KB
    int*            list2    = (int*)  (ws + 42283008);            // 256 KB
    int4*           c4       = (int4*) (ws + 42545152);            // 1 MB
    int*            counts   = (int*)  (ws + 43593728);            // 4 KB
    int*            nflag1   = (int*)  (ws + 43597824);            // 64 B
    int*            nflag2   = (int*)  (ws + 43597888);            // 64 B
    double*         loss_acc = (double*)(ws + 43597952);           // 8 B

    k_init   <<<dim3(1024), dim3(256), 0, stream>>>(E, Eh, Et, e2f, e2d, counts, nflag1, nflag2, loss_acc);
    k_zsplit <<<dim3(2048), dim3(256), 0, stream>>>(Z, Zh, S1);
    k_phase1 <<<dim3(4096), dim3(256), 0, stream>>>(Zh, Eh, e2f, pm1, pm2, pi1);
    k_merge  <<<dim3(256),  dim3(256), 0, stream>>>(pm1, pm2, pi1, S1, idx, counts, flag, list1, nflag1);
    k_candsel<<<dim3(64),   dim3(256), 0, stream>>>(Zh, Eh, e2f, S1, list1, nflag1, c4, flag, list2, nflag2);
    k_rescan <<<dim3(512),  dim3(256), 0, stream>>>(Z, Et, e2d, list2, nflag2, idx, counts);
    k_gather <<<dim3(2048), dim3(256), 0, stream>>>(Z, E, idx, flag, c4, out + 1, counts, loss_acc);
    k_final  <<<1,          dim3(256), 0, stream>>>(counts, loss_acc, out);
}